// Round 8
// baseline (290.351 us; speedup 1.0000x reference)
//
#include <hip/hip_runtime.h>
#include <hip/hip_bf16.h>

typedef __attribute__((ext_vector_type(8))) short short8;
typedef __attribute__((ext_vector_type(4))) float f32x4;

static inline size_t ws_align(size_t x) { return (x + 511) & ~((size_t)511); }

static __device__ inline unsigned short f2bf(float f) {
    __hip_bfloat16 h = __float2bfloat16(f);
    return __builtin_bit_cast(unsigned short, h);
}

static __device__ inline float bf2f(unsigned short u) {
    unsigned int x = ((unsigned int)u) << 16;
    return __builtin_bit_cast(float, x);
}

// ---------------- K0: W pre-transpose -> bf16 Wt[n][k] (wave-local dtype sniff) ----------------
__global__ __launch_bounds__(256) void wconv_kernel(const unsigned short* __restrict__ w1s,
                                                    const void* __restrict__ W1raw,
                                                    const void* __restrict__ W2raw,
                                                    const void* __restrict__ W3raw,
                                                    unsigned short* __restrict__ wt1,
                                                    unsigned short* __restrict__ wt2,
                                                    unsigned short* __restrict__ wt3) {
    const int tid = threadIdx.x;
    const int lane = tid & 63;
    unsigned ew = (w1s[2 * lane] >> 7) & 0xFF;
    unsigned long long m1 = __ballot(ew >= 100 && ew <= 130);
    const int in_fp32 = (__popcll(m1) < 48) ? 1 : 0;

    int idx = blockIdx.x * 256 + tid;
    const void* src;
    unsigned short* dst;
    int e, fout;
    if (idx < 16384) {
        src = W1raw; dst = wt1; e = idx; fout = 128;
    } else if (idx < 32768) {
        src = W2raw; dst = wt2; e = idx - 16384; fout = 128;
    } else if (idx < 40960) {
        src = W3raw; dst = wt3; e = idx - 32768; fout = 64;
    } else {
        return;
    }
    int n = e & (fout - 1);
    int k = e / fout;
    unsigned short v;
    if (in_fp32) v = f2bf(((const float*)src)[e]);
    else         v = ((const unsigned short*)src)[e];
    dst[n * 128 + k] = v;
}

// ---------------- K1: gemm1 (fine-grain, 16 rows/block) || hist ----------------
// Blocks [0, gblocks): gemm1 — block owns 16 rows; wave w owns col-tiles {2w, 2w+1}.
// Blocks [gblocks, gblocks+hblocks): hist + flag publish.
// 12500 gemm waves device-wide -> latency hidden (vs 1564 at the old 128-row grain).

__global__ __launch_bounds__(256) void gemm1_hist_kernel(const void* __restrict__ Xraw,
                                                         const unsigned short* __restrict__ w1s,
                                                         const int* __restrict__ ei,
                                                         const unsigned short* __restrict__ wt1,
                                                         int* __restrict__ counts,
                                                         int* __restrict__ loff,
                                                         int* __restrict__ flags,
                                                         unsigned short* __restrict__ out,
                                                         int N, int E, int gblocks) {
    const int tid = threadIdx.x;
    const int lane = tid & 63;

    unsigned ew = (w1s[2 * lane] >> 7) & 0xFF;
    unsigned long long m1 = __ballot(ew >= 100 && ew <= 130);
    const int in_fp32 = (__popcll(m1) < 48) ? 1 : 0;

    if (blockIdx.x >= gblocks) {
        unsigned long long m2 = __ballot(((const unsigned int*)ei)[2 * lane + 1] == 0u);
        const int ei64 = (__popcll(m2) >= 48) ? 1 : 0;
        if (blockIdx.x == gblocks && tid == 0) {
            flags[0] = in_fp32;
            flags[1] = ei64;
        }
        int e = (blockIdx.x - gblocks) * 256 + tid;
        if (e < E) {
            int d = ei64 ? ei[2 * (size_t)E + 2 * e] : ei[(size_t)E + e];
            loff[e] = atomicAdd(&counts[d], 1);
        }
        return;
    }

    const int wave = tid >> 6;
    const int quad = lane >> 4;
    const int r16 = lane & 15;
    const int base = blockIdx.x * 16;

    int arow = base + r16;
    if (arow > N - 1) arow = N - 1;

    short8 afrag[4];
    if (in_fp32) {
        const float* Ap = (const float*)Xraw + (size_t)arow * 128 + quad * 8;
#pragma unroll
        for (int kk = 0; kk < 4; kk++) {
            float4 f0 = *(const float4*)(const void*)(Ap + kk * 32);
            float4 f1 = *(const float4*)(const void*)(Ap + kk * 32 + 4);
            short8 r;
            r[0] = (short)f2bf(f0.x); r[1] = (short)f2bf(f0.y);
            r[2] = (short)f2bf(f0.z); r[3] = (short)f2bf(f0.w);
            r[4] = (short)f2bf(f1.x); r[5] = (short)f2bf(f1.y);
            r[6] = (short)f2bf(f1.z); r[7] = (short)f2bf(f1.w);
            afrag[kk] = r;
        }
    } else {
        const unsigned short* Ap = (const unsigned short*)Xraw + (size_t)arow * 128 + quad * 8;
#pragma unroll
        for (int kk = 0; kk < 4; kk++) afrag[kk] = *(const short8*)(const void*)(Ap + kk * 32);
    }

    f32x4 acc[2];
#pragma unroll
    for (int t = 0; t < 2; t++) acc[t] = (f32x4){0.f, 0.f, 0.f, 0.f};

#pragma unroll
    for (int kk = 0; kk < 4; kk++) {
#pragma unroll
        for (int t = 0; t < 2; t++) {
            int ntg = wave * 2 + t;
            short8 b = *(const short8*)(const void*)(wt1 + (size_t)(ntg * 16 + r16) * 128 + kk * 32 + quad * 8);
            acc[t] = __builtin_amdgcn_mfma_f32_16x16x32_bf16(afrag[kk], b, acc[t], 0, 0, 0);
        }
    }

#pragma unroll
    for (int t = 0; t < 2; t++) {
        int ntg = wave * 2 + t;
#pragma unroll
        for (int r = 0; r < 4; r++) {
            float v = acc[t][r];
            float o = __shfl_xor(v, 1, 64);
            int row = base + quad * 4 + r;
            if (((lane & 1) == 0) && row < N) {
                __hip_bfloat162 pk;
                pk.x = __float2bfloat16(v);
                pk.y = __float2bfloat16(o);
                *(__hip_bfloat162*)(out + (size_t)row * 128 + ntg * 16 + r16) = pk;
            }
        }
    }
}

// ---------------- GEMM (layers 2,3): fine-grain, A bf16 internal, B from global Wt ----------------
// Block = 16 rows; wave w owns FOUT/64 col-tiles. 3125 blocks -> 12500 waves.

template <int FOUT>
__global__ __launch_bounds__(256) void gemm_kernel(const unsigned short* __restrict__ A,
                                                   const unsigned short* __restrict__ wt,
                                                   unsigned short* __restrict__ out, int N) {
    constexpr int TPW = FOUT / 64;  // col-tiles per wave
    const int tid = threadIdx.x;
    const int wave = tid >> 6;
    const int lane = tid & 63;
    const int quad = lane >> 4;
    const int r16 = lane & 15;
    const int base = blockIdx.x * 16;

    int arow = base + r16;
    if (arow > N - 1) arow = N - 1;
    const unsigned short* Ap = A + (size_t)arow * 128 + quad * 8;

    short8 afrag[4];
#pragma unroll
    for (int kk = 0; kk < 4; kk++) afrag[kk] = *(const short8*)(const void*)(Ap + kk * 32);

    f32x4 acc[TPW];
#pragma unroll
    for (int t = 0; t < TPW; t++) acc[t] = (f32x4){0.f, 0.f, 0.f, 0.f};

#pragma unroll
    for (int kk = 0; kk < 4; kk++) {
#pragma unroll
        for (int t = 0; t < TPW; t++) {
            int ntg = wave * TPW + t;
            short8 b = *(const short8*)(const void*)(wt + (size_t)(ntg * 16 + r16) * 128 + kk * 32 + quad * 8);
            acc[t] = __builtin_amdgcn_mfma_f32_16x16x32_bf16(afrag[kk], b, acc[t], 0, 0, 0);
        }
    }

#pragma unroll
    for (int t = 0; t < TPW; t++) {
        int ntg = wave * TPW + t;
#pragma unroll
        for (int r = 0; r < 4; r++) {
            float v = acc[t][r];
            float o = __shfl_xor(v, 1, 64);
            int row = base + quad * 4 + r;
            if (((lane & 1) == 0) && row < N) {
                __hip_bfloat162 pk;
                pk.x = __float2bfloat16(v);
                pk.y = __float2bfloat16(o);
                *(__hip_bfloat162*)(out + (size_t)row * FOUT + ntg * 16 + r16) = pk;
            }
        }
    }
}

// ---------------- CSR build (alloc + fill) ----------------

__global__ __launch_bounds__(256) void alloc_kernel(const int* __restrict__ counts,
                                                    float* __restrict__ dinv,
                                                    int* __restrict__ rowptr,
                                                    int* __restrict__ total, int N) {
    int n = blockIdx.x * blockDim.x + threadIdx.x;
    int lane = threadIdx.x & 63;
    int c = (n < N) ? counts[n] : 0;
    if (n < N) {
        int d = (c < 1) ? 1 : c;
        dinv[n] = rsqrtf((float)d);
    }
    int incl = c;
#pragma unroll
    for (int off = 1; off < 64; off <<= 1) {
        int v = __shfl_up(incl, off, 64);
        if (lane >= off) incl += v;
    }
    int wavetot = __shfl(incl, 63, 64);
    int base = 0;
    if (lane == 0) base = atomicAdd(total, wavetot);
    base = __shfl(base, 0, 64);
    if (n < N) rowptr[n] = base + incl - c;
}

__global__ void fill_kernel(const int* __restrict__ ei, const int* __restrict__ flags,
                            const float* __restrict__ dinv, const int* __restrict__ rowptr,
                            const int* __restrict__ loff, int2* __restrict__ edgedat, int E) {
    int e = blockIdx.x * blockDim.x + threadIdx.x;
    if (e < E) {
        int s, d;
        if (flags[1]) {
            s = ei[2 * e];
            d = ei[2 * (size_t)E + 2 * e];
        } else {
            s = ei[e];
            d = ei[(size_t)E + e];
        }
        int pos = rowptr[d] + loff[e];
        float wt = dinv[s] * dinv[d];
        edgedat[pos] = make_int2(s, __float_as_int(wt));
    }
}

// ---------------- SpMM: wave per node, 4 edges in flight (16-lane groups, 16B row slices) ----------------

__global__ __launch_bounds__(256) void spmm128_kernel(const int2* __restrict__ edgedat,
                                                      const int* __restrict__ rowptr,
                                                      const int* __restrict__ counts,
                                                      const unsigned short* __restrict__ Hin,
                                                      unsigned short* __restrict__ Hout, int N) {
    int wid = (blockIdx.x * 256 + threadIdx.x) >> 6;
    if (wid >= N) return;
    int lane = threadIdx.x & 63;
    int grp = lane >> 4;
    int gl = lane & 15;
    int n = __builtin_amdgcn_readfirstlane(wid);
    int start = __builtin_amdgcn_readfirstlane(rowptr[n]);
    int len = __builtin_amdgcn_readfirstlane(counts[n]);
    const int2* ep = edgedat + start;

    float acc[8];
#pragma unroll
    for (int u = 0; u < 8; u++) acc[u] = 0.f;

    int j = 0;
    for (; j + 8 <= len; j += 8) {
        int2 e0 = ep[j + grp];
        int2 e1 = ep[j + 4 + grp];
        short8 h0 = *(const short8*)(const void*)(Hin + (size_t)e0.x * 128 + gl * 8);
        short8 h1 = *(const short8*)(const void*)(Hin + (size_t)e1.x * 128 + gl * 8);
        float w0 = __int_as_float(e0.y);
        float w1 = __int_as_float(e1.y);
#pragma unroll
        for (int u = 0; u < 8; u++) acc[u] += w0 * bf2f((unsigned short)h0[u]);
#pragma unroll
        for (int u = 0; u < 8; u++) acc[u] += w1 * bf2f((unsigned short)h1[u]);
    }
    for (; j + 4 <= len; j += 4) {
        int2 e = ep[j + grp];
        short8 h = *(const short8*)(const void*)(Hin + (size_t)e.x * 128 + gl * 8);
        float w = __int_as_float(e.y);
#pragma unroll
        for (int u = 0; u < 8; u++) acc[u] += w * bf2f((unsigned short)h[u]);
    }
    int rem = len - j;
    if (grp < rem) {
        int2 e = ep[j + grp];
        short8 h = *(const short8*)(const void*)(Hin + (size_t)e.x * 128 + gl * 8);
        float w = __int_as_float(e.y);
#pragma unroll
        for (int u = 0; u < 8; u++) acc[u] += w * bf2f((unsigned short)h[u]);
    }

#pragma unroll
    for (int u = 0; u < 8; u++) {
        acc[u] += __shfl_xor(acc[u], 16, 64);
        acc[u] += __shfl_xor(acc[u], 32, 64);
    }

    if (grp == 0) {
        short8 o;
#pragma unroll
        for (int u = 0; u < 8; u++) o[u] = (short)f2bf(fmaxf(acc[u], 0.f));
        *(short8*)(void*)(Hout + (size_t)n * 128 + gl * 8) = o;
    }
}

// ---------------- SpMM F=64 + relu + softmax: 8 edges in flight (8-lane groups) ----------------

__global__ __launch_bounds__(256) void spmm64_softmax_kernel(const int2* __restrict__ edgedat,
                                                             const int* __restrict__ rowptr,
                                                             const int* __restrict__ counts,
                                                             const unsigned short* __restrict__ Hin,
                                                             const int* __restrict__ flags,
                                                             void* __restrict__ Out, int N) {
    int wid = (blockIdx.x * 256 + threadIdx.x) >> 6;
    if (wid >= N) return;
    int lane = threadIdx.x & 63;
    int grp = lane >> 3;
    int gl = lane & 7;
    int n = __builtin_amdgcn_readfirstlane(wid);
    int start = __builtin_amdgcn_readfirstlane(rowptr[n]);
    int len = __builtin_amdgcn_readfirstlane(counts[n]);
    const int2* ep = edgedat + start;

    float acc[8];
#pragma unroll
    for (int u = 0; u < 8; u++) acc[u] = 0.f;

    int j = 0;
    for (; j + 16 <= len; j += 16) {
        int2 e0 = ep[j + grp];
        int2 e1 = ep[j + 8 + grp];
        short8 h0 = *(const short8*)(const void*)(Hin + (size_t)e0.x * 64 + gl * 8);
        short8 h1 = *(const short8*)(const void*)(Hin + (size_t)e1.x * 64 + gl * 8);
        float w0 = __int_as_float(e0.y);
        float w1 = __int_as_float(e1.y);
#pragma unroll
        for (int u = 0; u < 8; u++) acc[u] += w0 * bf2f((unsigned short)h0[u]);
#pragma unroll
        for (int u = 0; u < 8; u++) acc[u] += w1 * bf2f((unsigned short)h1[u]);
    }
    for (; j + 8 <= len; j += 8) {
        int2 e = ep[j + grp];
        short8 h = *(const short8*)(const void*)(Hin + (size_t)e.x * 64 + gl * 8);
        float w = __int_as_float(e.y);
#pragma unroll
        for (int u = 0; u < 8; u++) acc[u] += w * bf2f((unsigned short)h[u]);
    }
    int rem = len - j;
    if (grp < rem) {
        int2 e = ep[j + grp];
        short8 h = *(const short8*)(const void*)(Hin + (size_t)e.x * 64 + gl * 8);
        float w = __int_as_float(e.y);
#pragma unroll
        for (int u = 0; u < 8; u++) acc[u] += w * bf2f((unsigned short)h[u]);
    }

#pragma unroll
    for (int u = 0; u < 8; u++) {
        acc[u] += __shfl_xor(acc[u], 8, 64);
        acc[u] += __shfl_xor(acc[u], 16, 64);
        acc[u] += __shfl_xor(acc[u], 32, 64);
    }

#pragma unroll
    for (int u = 0; u < 8; u++) acc[u] = fmaxf(acc[u], 0.f);

    float m = acc[0];
#pragma unroll
    for (int u = 1; u < 8; u++) m = fmaxf(m, acc[u]);
#pragma unroll
    for (int off = 1; off < 8; off <<= 1) m = fmaxf(m, __shfl_xor(m, off, 64));

    float ex[8];
    float s = 0.f;
#pragma unroll
    for (int u = 0; u < 8; u++) {
        ex[u] = __expf(acc[u] - m);
        s += ex[u];
    }
#pragma unroll
    for (int off = 1; off < 8; off <<= 1) s += __shfl_xor(s, off, 64);
    float inv = 1.0f / s;

    if (grp == 0) {
        if (flags[0]) {
            float* op = (float*)Out + (size_t)n * 64 + gl * 8;
            float4 v0, v1;
            v0.x = ex[0] * inv; v0.y = ex[1] * inv; v0.z = ex[2] * inv; v0.w = ex[3] * inv;
            v1.x = ex[4] * inv; v1.y = ex[5] * inv; v1.z = ex[6] * inv; v1.w = ex[7] * inv;
            *(float4*)(void*)op = v0;
            *(float4*)(void*)(op + 4) = v1;
        } else {
            short8 o;
#pragma unroll
            for (int u = 0; u < 8; u++) o[u] = (short)f2bf(ex[u] * inv);
            *(short8*)(void*)((unsigned short*)Out + (size_t)n * 64 + gl * 8) = o;
        }
    }
}

// ---------------- launch ----------------

extern "C" void kernel_launch(void* const* d_in, const int* in_sizes, int n_in,
                              void* d_out, int out_size, void* d_ws, size_t ws_size,
                              hipStream_t stream) {
    const void* X  = d_in[0];                       // [N,128] bf16 or fp32
    const int*  ei = (const int*)d_in[1];           // [2,E] int32 or int64
    const void* W1 = d_in[2];                       // [128,128]
    const void* W2 = d_in[3];                       // [128,128]
    const void* W3 = d_in[4];                       // [128,64]

    const int N = in_sizes[0] / 128;   // 50000
    const int E = in_sizes[1] / 2;     // 800000

    char* ws = (char*)d_ws;
    size_t off = 0;
    int* counts = (int*)(ws + off);   off += ws_align((size_t)N * 4);
    int* total  = (int*)(ws + off);   off += ws_align(64);
    const size_t zero_bytes = off;    // counts + total need zeroing
    int* flags    = (int*)(ws + off);   off += ws_align(64);
    int* rowptr   = (int*)(ws + off);   off += ws_align((size_t)N * 4);
    float* dinv   = (float*)(ws + off); off += ws_align((size_t)N * 4);
    int* loff     = (int*)(ws + off);   off += ws_align((size_t)E * 4);
    int2* edgedat = (int2*)(ws + off);  off += ws_align((size_t)E * 8);
    unsigned short* HA = (unsigned short*)(ws + off); off += ws_align((size_t)N * 128 * 2);
    unsigned short* HB = (unsigned short*)(ws + off); off += ws_align((size_t)N * 128 * 2);
    unsigned short* wt1 = (unsigned short*)(ws + off); off += ws_align(16384 * 2);
    unsigned short* wt2 = (unsigned short*)(ws + off); off += ws_align(16384 * 2);
    unsigned short* wt3 = (unsigned short*)(ws + off); off += ws_align(8192 * 2);

    hipMemsetAsync(d_ws, 0, zero_bytes, stream);

    const int gblocks = (N + 15) / 16;         // 3125
    const int hblocks = (E + 255) / 256;       // 3125
    const int sblocks = (N * 64 + 255) / 256;  // 12500

    // K0: build bf16 Wt (tiny)
    wconv_kernel<<<160, 256, 0, stream>>>((const unsigned short*)W1, W1, W2, W3, wt1, wt2, wt3);
    // K1: gemm1 (X @ W1 -> HA, fine-grain) || hist (counts/loff) + flag publish
    gemm1_hist_kernel<<<gblocks + hblocks, 256, 0, stream>>>(
        X, (const unsigned short*)W1, ei, wt1, counts, loff, flags, HA, N, E, gblocks);
    alloc_kernel<<<(N + 255) / 256, 256, 0, stream>>>(counts, dinv, rowptr, total, N);
    fill_kernel<<<hblocks, 256, 0, stream>>>(ei, flags, dinv, rowptr, loff, edgedat, E);

    // layer 1 aggregate: HB = relu(A_norm HA)
    spmm128_kernel<<<sblocks, 256, 0, stream>>>(edgedat, rowptr, counts, HA, HB, N);
    // layer 2
    gemm_kernel<128><<<gblocks, 256, 0, stream>>>(HB, wt2, HA, N);
    spmm128_kernel<<<sblocks, 256, 0, stream>>>(edgedat, rowptr, counts, HA, HB, N);
    // layer 3 (F_out = 64) + relu + softmax
    gemm_kernel<64><<<gblocks, 256, 0, stream>>>(HB, wt3, HA, N);
    spmm64_softmax_kernel<<<sblocks, 256, 0, stream>>>(edgedat, rowptr, counts, HA, flags, d_out, N);
}

// Round 9
// 276.493 us; speedup vs baseline: 1.0501x; 1.0501x over previous
//
#include <hip/hip_runtime.h>
#include <hip/hip_bf16.h>

typedef __attribute__((ext_vector_type(8))) short short8;
typedef __attribute__((ext_vector_type(4))) short short4v;
typedef __attribute__((ext_vector_type(4))) float f32x4;

static inline size_t ws_align(size_t x) { return (x + 511) & ~((size_t)511); }

static __device__ inline unsigned short f2bf(float f) {
    __hip_bfloat16 h = __float2bfloat16(f);
    return __builtin_bit_cast(unsigned short, h);
}

static __device__ inline float bf2f(unsigned short u) {
    unsigned int x = ((unsigned int)u) << 16;
    return __builtin_bit_cast(float, x);
}

// ---------------- shared GEMM block body: 64 rows, W+A staged in LDS ----------------
// bt[n][k] (n in [0,FOUT), k in [0,128)), LDB=136. atile[r][k], r in [0,64), LDA=136.
// 4 waves; wave owns rows wave*16..wave*16+15, all FOUT/16 col-tiles.

template <int FOUT>
static __device__ inline void gemm64_body(const void* __restrict__ Araw, int a_fp32,
                                          const void* __restrict__ Wraw, int w_fp32,
                                          unsigned short* __restrict__ out,
                                          int N, int blk) {
    constexpr int K = 128;
    constexpr int NT = FOUT / 16;
    constexpr int LDB = K + 8;
    constexpr int LDA = K + 8;
    __shared__ __align__(16) unsigned short bt[FOUT * LDB];
    __shared__ __align__(16) unsigned short atile[64 * LDA];

    const int tid = threadIdx.x;
    const int base = blk * 64;

    // ---- stage W (transpose + optional convert) ----
    constexpr int TOT4 = K * FOUT / 4;
    if (w_fp32) {
        const float* Wf = (const float*)Wraw;
        for (int i = tid; i < TOT4; i += 256) {
            int idx = i * 4;
            int k = idx / FOUT;
            int n = idx & (FOUT - 1);
            float4 v = *(const float4*)(const void*)(Wf + idx);
            bt[(n + 0) * LDB + k] = f2bf(v.x);
            bt[(n + 1) * LDB + k] = f2bf(v.y);
            bt[(n + 2) * LDB + k] = f2bf(v.z);
            bt[(n + 3) * LDB + k] = f2bf(v.w);
        }
    } else {
        const unsigned short* Ws = (const unsigned short*)Wraw;
        for (int i = tid; i < TOT4; i += 256) {
            int idx = i * 4;
            int k = idx / FOUT;
            int n = idx & (FOUT - 1);
            short4v v = *(const short4v*)(const void*)(Ws + idx);
#pragma unroll
            for (int j = 0; j < 4; j++) bt[(n + j) * LDB + k] = ((const unsigned short*)&v)[j];
        }
    }

    // ---- stage A tile (coalesced) ----
    if (a_fp32) {
        const float* Af = (const float*)Araw;
#pragma unroll
        for (int i = 0; i < 8; i++) {               // 2048 float4 / 256 threads
            int e4 = i * 256 + tid;
            int elem = e4 * 4;
            int r = elem >> 7;
            int c = elem & 127;
            int srow = base + r;
            if (srow > N - 1) srow = N - 1;
            float4 v = *(const float4*)(const void*)(Af + (size_t)srow * K + c);
            unsigned short* dst = &atile[r * LDA + c];
            dst[0] = f2bf(v.x); dst[1] = f2bf(v.y); dst[2] = f2bf(v.z); dst[3] = f2bf(v.w);
        }
    } else {
        const unsigned short* Ab = (const unsigned short*)Araw;
#pragma unroll
        for (int i = 0; i < 4; i++) {               // 1024 short8 / 256 threads
            int e8 = i * 256 + tid;
            int elem = e8 * 8;
            int r = elem >> 7;
            int c = elem & 127;
            int srow = base + r;
            if (srow > N - 1) srow = N - 1;
            *(short8*)(void*)(&atile[r * LDA + c]) =
                *(const short8*)(const void*)(Ab + (size_t)srow * K + c);
        }
    }

    __syncthreads();

    const int wave = tid >> 6;
    const int lane = tid & 63;
    const int quad = lane >> 4;
    const int r16 = lane & 15;

    short8 afrag[4];
#pragma unroll
    for (int kk = 0; kk < 4; kk++)
        afrag[kk] = *(const short8*)(const void*)(&atile[(wave * 16 + r16) * LDA + kk * 32 + quad * 8]);

    f32x4 acc[NT];
#pragma unroll
    for (int nt = 0; nt < NT; nt++) acc[nt] = (f32x4){0.f, 0.f, 0.f, 0.f};

#pragma unroll
    for (int kk = 0; kk < 4; kk++) {
#pragma unroll
        for (int nt = 0; nt < NT; nt++) {
            short8 b = *(const short8*)(const void*)(&bt[(nt * 16 + r16) * LDB + kk * 32 + quad * 8]);
            acc[nt] = __builtin_amdgcn_mfma_f32_16x16x32_bf16(afrag[kk], b, acc[nt], 0, 0, 0);
        }
    }

#pragma unroll
    for (int nt = 0; nt < NT; nt++) {
#pragma unroll
        for (int r = 0; r < 4; r++) {
            float v = acc[nt][r];
            float o = __shfl_xor(v, 1, 64);
            int row = base + wave * 16 + quad * 4 + r;
            if (((lane & 1) == 0) && row < N) {
                __hip_bfloat162 pk;
                pk.x = __float2bfloat16(v);
                pk.y = __float2bfloat16(o);
                *(__hip_bfloat162*)(out + (size_t)row * FOUT + nt * 16 + r16) = pk;
            }
        }
    }
}

// ---------------- K1: gemm1 (64-row blocks) || hist ----------------
// Blocks [0, gblocks): gemm1 (X @ W1 -> HA). Blocks [gblocks, gblocks+hblocks): hist + flags.

__global__ __launch_bounds__(256) void gemm1_hist_kernel(const void* __restrict__ Xraw,
                                                         const unsigned short* __restrict__ w1s,
                                                         const int* __restrict__ ei,
                                                         int* __restrict__ counts,
                                                         int* __restrict__ loff,
                                                         int* __restrict__ flags,
                                                         unsigned short* __restrict__ out,
                                                         int N, int E, int gblocks) {
    const int tid = threadIdx.x;
    const int lane = tid & 63;

    unsigned ew = (w1s[2 * lane] >> 7) & 0xFF;
    unsigned long long m1 = __ballot(ew >= 100 && ew <= 130);
    const int in_fp32 = (__popcll(m1) < 48) ? 1 : 0;

    if (blockIdx.x >= gblocks) {
        unsigned long long m2 = __ballot(((const unsigned int*)ei)[2 * lane + 1] == 0u);
        const int ei64 = (__popcll(m2) >= 48) ? 1 : 0;
        if (blockIdx.x == gblocks && tid == 0) {
            flags[0] = in_fp32;
            flags[1] = ei64;
        }
        int e = (blockIdx.x - gblocks) * 256 + tid;
        if (e < E) {
            int d = ei64 ? ei[2 * (size_t)E + 2 * e] : ei[(size_t)E + e];
            loff[e] = atomicAdd(&counts[d], 1);
        }
        return;
    }

    gemm64_body<128>(Xraw, in_fp32, (const void*)w1s, in_fp32, out, N, blockIdx.x);
}

// ---------------- GEMM (layers 2,3): A bf16 internal ----------------

template <int FOUT>
__global__ __launch_bounds__(256) void gemm_kernel(const void* __restrict__ Araw,
                                                   const void* __restrict__ Wraw,
                                                   const int* __restrict__ flags,
                                                   unsigned short* __restrict__ out, int N) {
    gemm64_body<FOUT>(Araw, 0, Wraw, flags[0], out, N, blockIdx.x);
}

// ---------------- CSR build (alloc + fill) ----------------

__global__ __launch_bounds__(256) void alloc_kernel(const int* __restrict__ counts,
                                                    float* __restrict__ dinv,
                                                    int* __restrict__ rowptr,
                                                    int* __restrict__ total, int N) {
    int n = blockIdx.x * blockDim.x + threadIdx.x;
    int lane = threadIdx.x & 63;
    int c = (n < N) ? counts[n] : 0;
    if (n < N) {
        int d = (c < 1) ? 1 : c;
        dinv[n] = rsqrtf((float)d);
    }
    int incl = c;
#pragma unroll
    for (int off = 1; off < 64; off <<= 1) {
        int v = __shfl_up(incl, off, 64);
        if (lane >= off) incl += v;
    }
    int wavetot = __shfl(incl, 63, 64);
    int base = 0;
    if (lane == 0) base = atomicAdd(total, wavetot);
    base = __shfl(base, 0, 64);
    if (n < N) rowptr[n] = base + incl - c;
}

__global__ void fill_kernel(const int* __restrict__ ei, const int* __restrict__ flags,
                            const float* __restrict__ dinv, const int* __restrict__ rowptr,
                            const int* __restrict__ loff, int2* __restrict__ edgedat, int E) {
    int e = blockIdx.x * blockDim.x + threadIdx.x;
    if (e < E) {
        int s, d;
        if (flags[1]) {
            s = ei[2 * e];
            d = ei[2 * (size_t)E + 2 * e];
        } else {
            s = ei[e];
            d = ei[(size_t)E + e];
        }
        int pos = rowptr[d] + loff[e];
        float wt = dinv[s] * dinv[d];
        edgedat[pos] = make_int2(s, __float_as_int(wt));
    }
}

// ---------------- SpMM: wave per node, 4 edges in flight (16-lane groups, 16B row slices) ----------------

__global__ __launch_bounds__(256) void spmm128_kernel(const int2* __restrict__ edgedat,
                                                      const int* __restrict__ rowptr,
                                                      const int* __restrict__ counts,
                                                      const unsigned short* __restrict__ Hin,
                                                      unsigned short* __restrict__ Hout, int N) {
    int wid = (blockIdx.x * 256 + threadIdx.x) >> 6;
    if (wid >= N) return;
    int lane = threadIdx.x & 63;
    int grp = lane >> 4;
    int gl = lane & 15;
    int n = __builtin_amdgcn_readfirstlane(wid);
    int start = __builtin_amdgcn_readfirstlane(rowptr[n]);
    int len = __builtin_amdgcn_readfirstlane(counts[n]);
    const int2* ep = edgedat + start;

    float acc[8];
#pragma unroll
    for (int u = 0; u < 8; u++) acc[u] = 0.f;

    int j = 0;
    for (; j + 8 <= len; j += 8) {
        int2 e0 = ep[j + grp];
        int2 e1 = ep[j + 4 + grp];
        short8 h0 = *(const short8*)(const void*)(Hin + (size_t)e0.x * 128 + gl * 8);
        short8 h1 = *(const short8*)(const void*)(Hin + (size_t)e1.x * 128 + gl * 8);
        float w0 = __int_as_float(e0.y);
        float w1 = __int_as_float(e1.y);
#pragma unroll
        for (int u = 0; u < 8; u++) acc[u] += w0 * bf2f((unsigned short)h0[u]);
#pragma unroll
        for (int u = 0; u < 8; u++) acc[u] += w1 * bf2f((unsigned short)h1[u]);
    }
    for (; j + 4 <= len; j += 4) {
        int2 e = ep[j + grp];
        short8 h = *(const short8*)(const void*)(Hin + (size_t)e.x * 128 + gl * 8);
        float w = __int_as_float(e.y);
#pragma unroll
        for (int u = 0; u < 8; u++) acc[u] += w * bf2f((unsigned short)h[u]);
    }
    int rem = len - j;
    if (grp < rem) {
        int2 e = ep[j + grp];
        short8 h = *(const short8*)(const void*)(Hin + (size_t)e.x * 128 + gl * 8);
        float w = __int_as_float(e.y);
#pragma unroll
        for (int u = 0; u < 8; u++) acc[u] += w * bf2f((unsigned short)h[u]);
    }

#pragma unroll
    for (int u = 0; u < 8; u++) {
        acc[u] += __shfl_xor(acc[u], 16, 64);
        acc[u] += __shfl_xor(acc[u], 32, 64);
    }

    if (grp == 0) {
        short8 o;
#pragma unroll
        for (int u = 0; u < 8; u++) o[u] = (short)f2bf(fmaxf(acc[u], 0.f));
        *(short8*)(void*)(Hout + (size_t)n * 128 + gl * 8) = o;
    }
}

// ---------------- SpMM F=64 + relu + softmax: 8 edges in flight (8-lane groups) ----------------

__global__ __launch_bounds__(256) void spmm64_softmax_kernel(const int2* __restrict__ edgedat,
                                                             const int* __restrict__ rowptr,
                                                             const int* __restrict__ counts,
                                                             const unsigned short* __restrict__ Hin,
                                                             const int* __restrict__ flags,
                                                             void* __restrict__ Out, int N) {
    int wid = (blockIdx.x * 256 + threadIdx.x) >> 6;
    if (wid >= N) return;
    int lane = threadIdx.x & 63;
    int grp = lane >> 3;
    int gl = lane & 7;
    int n = __builtin_amdgcn_readfirstlane(wid);
    int start = __builtin_amdgcn_readfirstlane(rowptr[n]);
    int len = __builtin_amdgcn_readfirstlane(counts[n]);
    const int2* ep = edgedat + start;

    float acc[8];
#pragma unroll
    for (int u = 0; u < 8; u++) acc[u] = 0.f;

    int j = 0;
    for (; j + 16 <= len; j += 16) {
        int2 e0 = ep[j + grp];
        int2 e1 = ep[j + 8 + grp];
        short8 h0 = *(const short8*)(const void*)(Hin + (size_t)e0.x * 64 + gl * 8);
        short8 h1 = *(const short8*)(const void*)(Hin + (size_t)e1.x * 64 + gl * 8);
        float w0 = __int_as_float(e0.y);
        float w1 = __int_as_float(e1.y);
#pragma unroll
        for (int u = 0; u < 8; u++) acc[u] += w0 * bf2f((unsigned short)h0[u]);
#pragma unroll
        for (int u = 0; u < 8; u++) acc[u] += w1 * bf2f((unsigned short)h1[u]);
    }
    for (; j + 8 <= len; j += 8) {
        int2 e = ep[j + grp];
        short8 h = *(const short8*)(const void*)(Hin + (size_t)e.x * 64 + gl * 8);
        float w = __int_as_float(e.y);
#pragma unroll
        for (int u = 0; u < 8; u++) acc[u] += w * bf2f((unsigned short)h[u]);
    }
    int rem = len - j;
    if (grp < rem) {
        int2 e = ep[j + grp];
        short8 h = *(const short8*)(const void*)(Hin + (size_t)e.x * 64 + gl * 8);
        float w = __int_as_float(e.y);
#pragma unroll
        for (int u = 0; u < 8; u++) acc[u] += w * bf2f((unsigned short)h[u]);
    }

#pragma unroll
    for (int u = 0; u < 8; u++) {
        acc[u] += __shfl_xor(acc[u], 8, 64);
        acc[u] += __shfl_xor(acc[u], 16, 64);
        acc[u] += __shfl_xor(acc[u], 32, 64);
    }

#pragma unroll
    for (int u = 0; u < 8; u++) acc[u] = fmaxf(acc[u], 0.f);

    float m = acc[0];
#pragma unroll
    for (int u = 1; u < 8; u++) m = fmaxf(m, acc[u]);
#pragma unroll
    for (int off = 1; off < 8; off <<= 1) m = fmaxf(m, __shfl_xor(m, off, 64));

    float ex[8];
    float s = 0.f;
#pragma unroll
    for (int u = 0; u < 8; u++) {
        ex[u] = __expf(acc[u] - m);
        s += ex[u];
    }
#pragma unroll
    for (int off = 1; off < 8; off <<= 1) s += __shfl_xor(s, off, 64);
    float inv = 1.0f / s;

    if (grp == 0) {
        if (flags[0]) {
            float* op = (float*)Out + (size_t)n * 64 + gl * 8;
            float4 v0, v1;
            v0.x = ex[0] * inv; v0.y = ex[1] * inv; v0.z = ex[2] * inv; v0.w = ex[3] * inv;
            v1.x = ex[4] * inv; v1.y = ex[5] * inv; v1.z = ex[6] * inv; v1.w = ex[7] * inv;
            *(float4*)(void*)op = v0;
            *(float4*)(void*)(op + 4) = v1;
        } else {
            short8 o;
#pragma unroll
            for (int u = 0; u < 8; u++) o[u] = (short)f2bf(ex[u] * inv);
            *(short8*)(void*)((unsigned short*)Out + (size_t)n * 64 + gl * 8) = o;
        }
    }
}

// ---------------- launch ----------------

extern "C" void kernel_launch(void* const* d_in, const int* in_sizes, int n_in,
                              void* d_out, int out_size, void* d_ws, size_t ws_size,
                              hipStream_t stream) {
    const void* X  = d_in[0];                       // [N,128] bf16 or fp32
    const int*  ei = (const int*)d_in[1];           // [2,E] int32 or int64
    const void* W1 = d_in[2];                       // [128,128]
    const void* W2 = d_in[3];                       // [128,128]
    const void* W3 = d_in[4];                       // [128,64]

    const int N = in_sizes[0] / 128;   // 50000
    const int E = in_sizes[1] / 2;     // 800000

    char* ws = (char*)d_ws;
    size_t off = 0;
    int* counts = (int*)(ws + off);   off += ws_align((size_t)N * 4);
    int* total  = (int*)(ws + off);   off += ws_align(64);
    const size_t zero_bytes = off;    // counts + total need zeroing
    int* flags    = (int*)(ws + off);   off += ws_align(64);
    int* rowptr   = (int*)(ws + off);   off += ws_align((size_t)N * 4);
    float* dinv   = (float*)(ws + off); off += ws_align((size_t)N * 4);
    int* loff     = (int*)(ws + off);   off += ws_align((size_t)E * 4);
    int2* edgedat = (int2*)(ws + off);  off += ws_align((size_t)E * 8);
    unsigned short* HA = (unsigned short*)(ws + off); off += ws_align((size_t)N * 128 * 2);
    unsigned short* HB = (unsigned short*)(ws + off); off += ws_align((size_t)N * 128 * 2);

    hipMemsetAsync(d_ws, 0, zero_bytes, stream);

    const int gblocks = (N + 63) / 64;         // 782
    const int hblocks = (E + 255) / 256;       // 3125
    const int sblocks = (N * 64 + 255) / 256;  // 12500

    // K1: gemm1 (X @ W1 -> HA, 64-row LDS-staged blocks) || hist + flag publish
    gemm1_hist_kernel<<<gblocks + hblocks, 256, 0, stream>>>(
        X, (const unsigned short*)W1, ei, counts, loff, flags, HA, N, E, gblocks);
    alloc_kernel<<<(N + 255) / 256, 256, 0, stream>>>(counts, dinv, rowptr, total, N);
    fill_kernel<<<hblocks, 256, 0, stream>>>(ei, flags, dinv, rowptr, loff, edgedat, E);

    // layer 1 aggregate: HB = relu(A_norm HA)
    spmm128_kernel<<<sblocks, 256, 0, stream>>>(edgedat, rowptr, counts, HA, HB, N);
    // layer 2
    gemm_kernel<128><<<gblocks, 256, 0, stream>>>(HB, W2, flags, HA, N);
    spmm128_kernel<<<sblocks, 256, 0, stream>>>(edgedat, rowptr, counts, HA, HB, N);
    // layer 3 (F_out = 64) + relu + softmax
    gemm_kernel<64><<<gblocks, 256, 0, stream>>>(HB, W3, flags, HA, N);
    spmm64_softmax_kernel<<<sblocks, 256, 0, stream>>>(edgedat, rowptr, counts, HA, flags, d_out, N);
}

// Round 10
// 257.742 us; speedup vs baseline: 1.1265x; 1.0727x over previous
//
#include <hip/hip_runtime.h>
#include <hip/hip_bf16.h>

typedef __attribute__((ext_vector_type(8))) short short8;
typedef __attribute__((ext_vector_type(4))) short short4v;
typedef __attribute__((ext_vector_type(4))) float f32x4;

static inline size_t ws_align(size_t x) { return (x + 511) & ~((size_t)511); }

static __device__ inline unsigned short f2bf(float f) {
    __hip_bfloat16 h = __float2bfloat16(f);
    return __builtin_bit_cast(unsigned short, h);
}

static __device__ inline float bf2f(unsigned short u) {
    unsigned int x = ((unsigned int)u) << 16;
    return __builtin_bit_cast(float, x);
}

// ---------------- shared GEMM block body: 512 threads = 8 waves, 128 rows, W in LDS ----------------
// bt[n][k], LDB=136 (34KB for FOUT=128, 17KB for FOUT=64). Wave w owns rows w*16..w*16+15,
// all FOUT/16 col-tiles (32 MFMAs for FOUT=128). 8 waves/block doubles occupancy vs 4-wave R6.

template <int FOUT>
static __device__ inline void gemm128_body(const void* __restrict__ Araw, int a_fp32,
                                           const void* __restrict__ Wraw, int w_fp32,
                                           unsigned short* __restrict__ out,
                                           int N, int blk) {
    constexpr int K = 128;
    constexpr int NT = FOUT / 16;
    constexpr int LDB = K + 8;
    __shared__ __align__(16) unsigned short bt[FOUT * LDB];

    const int tid = threadIdx.x;  // 0..511
    const int base = blk * 128;

    // ---- stage W (transpose + optional convert), 512 threads ----
    constexpr int TOT4 = K * FOUT / 4;
    if (w_fp32) {
        const float* Wf = (const float*)Wraw;
        for (int i = tid; i < TOT4; i += 512) {
            int idx = i * 4;
            int k = idx / FOUT;
            int n = idx & (FOUT - 1);
            float4 v = *(const float4*)(const void*)(Wf + idx);
            bt[(n + 0) * LDB + k] = f2bf(v.x);
            bt[(n + 1) * LDB + k] = f2bf(v.y);
            bt[(n + 2) * LDB + k] = f2bf(v.z);
            bt[(n + 3) * LDB + k] = f2bf(v.w);
        }
    } else {
        const unsigned short* Ws = (const unsigned short*)Wraw;
        for (int i = tid; i < TOT4; i += 512) {
            int idx = i * 4;
            int k = idx / FOUT;
            int n = idx & (FOUT - 1);
            short4v v = *(const short4v*)(const void*)(Ws + idx);
#pragma unroll
            for (int j = 0; j < 4; j++) bt[(n + j) * LDB + k] = ((const unsigned short*)&v)[j];
        }
    }

    const int wave = tid >> 6;    // 0..7
    const int lane = tid & 63;
    const int quad = lane >> 4;
    const int r16 = lane & 15;

    int arow = base + wave * 16 + r16;
    if (arow > N - 1) arow = N - 1;

    short8 afrag[4];
    if (a_fp32) {
        const float* Ap = (const float*)Araw + (size_t)arow * K + quad * 8;
#pragma unroll
        for (int kk = 0; kk < 4; kk++) {
            float4 f0 = *(const float4*)(const void*)(Ap + kk * 32);
            float4 f1 = *(const float4*)(const void*)(Ap + kk * 32 + 4);
            short8 r;
            r[0] = (short)f2bf(f0.x); r[1] = (short)f2bf(f0.y);
            r[2] = (short)f2bf(f0.z); r[3] = (short)f2bf(f0.w);
            r[4] = (short)f2bf(f1.x); r[5] = (short)f2bf(f1.y);
            r[6] = (short)f2bf(f1.z); r[7] = (short)f2bf(f1.w);
            afrag[kk] = r;
        }
    } else {
        const unsigned short* Ap = (const unsigned short*)Araw + (size_t)arow * K + quad * 8;
#pragma unroll
        for (int kk = 0; kk < 4; kk++) afrag[kk] = *(const short8*)(const void*)(Ap + kk * 32);
    }

    __syncthreads();

    f32x4 acc[NT];
#pragma unroll
    for (int nt = 0; nt < NT; nt++) acc[nt] = (f32x4){0.f, 0.f, 0.f, 0.f};

#pragma unroll
    for (int kk = 0; kk < 4; kk++) {
#pragma unroll
        for (int nt = 0; nt < NT; nt++) {
            short8 b = *(const short8*)(const void*)(&bt[(nt * 16 + r16) * LDB + kk * 32 + quad * 8]);
            acc[nt] = __builtin_amdgcn_mfma_f32_16x16x32_bf16(afrag[kk], b, acc[nt], 0, 0, 0);
        }
    }

#pragma unroll
    for (int nt = 0; nt < NT; nt++) {
#pragma unroll
        for (int r = 0; r < 4; r++) {
            float v = acc[nt][r];
            float o = __shfl_xor(v, 1, 64);
            int row = base + wave * 16 + quad * 4 + r;
            if (((lane & 1) == 0) && row < N) {
                __hip_bfloat162 pk;
                pk.x = __float2bfloat16(v);
                pk.y = __float2bfloat16(o);
                *(__hip_bfloat162*)(out + (size_t)row * FOUT + nt * 16 + r16) = pk;
            }
        }
    }
}

// ---------------- K1: gemm1 (512-thr, 128-row blocks) || hist ----------------

__global__ __launch_bounds__(512) void gemm1_hist_kernel(const void* __restrict__ Xraw,
                                                         const unsigned short* __restrict__ w1s,
                                                         const int* __restrict__ ei,
                                                         int* __restrict__ counts,
                                                         int* __restrict__ loff,
                                                         int* __restrict__ flags,
                                                         unsigned short* __restrict__ out,
                                                         int N, int E, int gblocks) {
    const int tid = threadIdx.x;
    const int lane = tid & 63;

    unsigned ew = (w1s[2 * lane] >> 7) & 0xFF;
    unsigned long long m1 = __ballot(ew >= 100 && ew <= 130);
    const int in_fp32 = (__popcll(m1) < 48) ? 1 : 0;

    if (blockIdx.x >= gblocks) {
        unsigned long long m2 = __ballot(((const unsigned int*)ei)[2 * lane + 1] == 0u);
        const int ei64 = (__popcll(m2) >= 48) ? 1 : 0;
        if (blockIdx.x == gblocks && tid == 0) {
            flags[0] = in_fp32;
            flags[1] = ei64;
        }
        int e = (blockIdx.x - gblocks) * 512 + tid;
        if (e < E) {
            int d = ei64 ? ei[2 * (size_t)E + 2 * e] : ei[(size_t)E + e];
            loff[e] = atomicAdd(&counts[d], 1);
        }
        return;
    }

    gemm128_body<128>(Xraw, in_fp32, (const void*)w1s, in_fp32, out, N, blockIdx.x);
}

// ---------------- GEMM (layers 2,3): A bf16 internal ----------------

template <int FOUT>
__global__ __launch_bounds__(512) void gemm_kernel(const void* __restrict__ Araw,
                                                   const void* __restrict__ Wraw,
                                                   const int* __restrict__ flags,
                                                   unsigned short* __restrict__ out, int N) {
    gemm128_body<FOUT>(Araw, 0, Wraw, flags[0], out, N, blockIdx.x);
}

// ---------------- CSR build (alloc + fill) ----------------

__global__ __launch_bounds__(256) void alloc_kernel(const int* __restrict__ counts,
                                                    float* __restrict__ dinv,
                                                    int* __restrict__ rowptr,
                                                    int* __restrict__ total, int N) {
    int n = blockIdx.x * blockDim.x + threadIdx.x;
    int lane = threadIdx.x & 63;
    int c = (n < N) ? counts[n] : 0;
    if (n < N) {
        int d = (c < 1) ? 1 : c;
        dinv[n] = rsqrtf((float)d);
    }
    int incl = c;
#pragma unroll
    for (int off = 1; off < 64; off <<= 1) {
        int v = __shfl_up(incl, off, 64);
        if (lane >= off) incl += v;
    }
    int wavetot = __shfl(incl, 63, 64);
    int base = 0;
    if (lane == 0) base = atomicAdd(total, wavetot);
    base = __shfl(base, 0, 64);
    if (n < N) rowptr[n] = base + incl - c;
}

__global__ void fill_kernel(const int* __restrict__ ei, const int* __restrict__ flags,
                            const float* __restrict__ dinv, const int* __restrict__ rowptr,
                            const int* __restrict__ loff, int2* __restrict__ edgedat, int E) {
    int e = blockIdx.x * blockDim.x + threadIdx.x;
    if (e < E) {
        int s, d;
        if (flags[1]) {
            s = ei[2 * e];
            d = ei[2 * (size_t)E + 2 * e];
        } else {
            s = ei[e];
            d = ei[(size_t)E + e];
        }
        int pos = rowptr[d] + loff[e];
        float wt = dinv[s] * dinv[d];
        edgedat[pos] = make_int2(s, __float_as_int(wt));
    }
}

// ---------------- SpMM: wave per node, 4 edges in flight (16-lane groups, 16B row slices) ----------------

__global__ __launch_bounds__(256) void spmm128_kernel(const int2* __restrict__ edgedat,
                                                      const int* __restrict__ rowptr,
                                                      const int* __restrict__ counts,
                                                      const unsigned short* __restrict__ Hin,
                                                      unsigned short* __restrict__ Hout, int N) {
    int wid = (blockIdx.x * 256 + threadIdx.x) >> 6;
    if (wid >= N) return;
    int lane = threadIdx.x & 63;
    int grp = lane >> 4;
    int gl = lane & 15;
    int n = __builtin_amdgcn_readfirstlane(wid);
    int start = __builtin_amdgcn_readfirstlane(rowptr[n]);
    int len = __builtin_amdgcn_readfirstlane(counts[n]);
    const int2* ep = edgedat + start;

    float acc[8];
#pragma unroll
    for (int u = 0; u < 8; u++) acc[u] = 0.f;

    int j = 0;
    for (; j + 8 <= len; j += 8) {
        int2 e0 = ep[j + grp];
        int2 e1 = ep[j + 4 + grp];
        short8 h0 = *(const short8*)(const void*)(Hin + (size_t)e0.x * 128 + gl * 8);
        short8 h1 = *(const short8*)(const void*)(Hin + (size_t)e1.x * 128 + gl * 8);
        float w0 = __int_as_float(e0.y);
        float w1 = __int_as_float(e1.y);
#pragma unroll
        for (int u = 0; u < 8; u++) acc[u] += w0 * bf2f((unsigned short)h0[u]);
#pragma unroll
        for (int u = 0; u < 8; u++) acc[u] += w1 * bf2f((unsigned short)h1[u]);
    }
    for (; j + 4 <= len; j += 4) {
        int2 e = ep[j + grp];
        short8 h = *(const short8*)(const void*)(Hin + (size_t)e.x * 128 + gl * 8);
        float w = __int_as_float(e.y);
#pragma unroll
        for (int u = 0; u < 8; u++) acc[u] += w * bf2f((unsigned short)h[u]);
    }
    int rem = len - j;
    if (grp < rem) {
        int2 e = ep[j + grp];
        short8 h = *(const short8*)(const void*)(Hin + (size_t)e.x * 128 + gl * 8);
        float w = __int_as_float(e.y);
#pragma unroll
        for (int u = 0; u < 8; u++) acc[u] += w * bf2f((unsigned short)h[u]);
    }

#pragma unroll
    for (int u = 0; u < 8; u++) {
        acc[u] += __shfl_xor(acc[u], 16, 64);
        acc[u] += __shfl_xor(acc[u], 32, 64);
    }

    if (grp == 0) {
        short8 o;
#pragma unroll
        for (int u = 0; u < 8; u++) o[u] = (short)f2bf(fmaxf(acc[u], 0.f));
        *(short8*)(void*)(Hout + (size_t)n * 128 + gl * 8) = o;
    }
}

// ---------------- SpMM F=64 + relu + softmax: 8 edges in flight (8-lane groups) ----------------

__global__ __launch_bounds__(256) void spmm64_softmax_kernel(const int2* __restrict__ edgedat,
                                                             const int* __restrict__ rowptr,
                                                             const int* __restrict__ counts,
                                                             const unsigned short* __restrict__ Hin,
                                                             const int* __restrict__ flags,
                                                             void* __restrict__ Out, int N) {
    int wid = (blockIdx.x * 256 + threadIdx.x) >> 6;
    if (wid >= N) return;
    int lane = threadIdx.x & 63;
    int grp = lane >> 3;
    int gl = lane & 7;
    int n = __builtin_amdgcn_readfirstlane(wid);
    int start = __builtin_amdgcn_readfirstlane(rowptr[n]);
    int len = __builtin_amdgcn_readfirstlane(counts[n]);
    const int2* ep = edgedat + start;

    float acc[8];
#pragma unroll
    for (int u = 0; u < 8; u++) acc[u] = 0.f;

    int j = 0;
    for (; j + 16 <= len; j += 16) {
        int2 e0 = ep[j + grp];
        int2 e1 = ep[j + 8 + grp];
        short8 h0 = *(const short8*)(const void*)(Hin + (size_t)e0.x * 64 + gl * 8);
        short8 h1 = *(const short8*)(const void*)(Hin + (size_t)e1.x * 64 + gl * 8);
        float w0 = __int_as_float(e0.y);
        float w1 = __int_as_float(e1.y);
#pragma unroll
        for (int u = 0; u < 8; u++) acc[u] += w0 * bf2f((unsigned short)h0[u]);
#pragma unroll
        for (int u = 0; u < 8; u++) acc[u] += w1 * bf2f((unsigned short)h1[u]);
    }
    for (; j + 8 <= len; j += 8) {
        int2 e = ep[j + grp];
        short8 h = *(const short8*)(const void*)(Hin + (size_t)e.x * 64 + gl * 8);
        float w = __int_as_float(e.y);
#pragma unroll
        for (int u = 0; u < 8; u++) acc[u] += w * bf2f((unsigned short)h[u]);
    }
    int rem = len - j;
    if (grp < rem) {
        int2 e = ep[j + grp];
        short8 h = *(const short8*)(const void*)(Hin + (size_t)e.x * 64 + gl * 8);
        float w = __int_as_float(e.y);
#pragma unroll
        for (int u = 0; u < 8; u++) acc[u] += w * bf2f((unsigned short)h[u]);
    }

#pragma unroll
    for (int u = 0; u < 8; u++) {
        acc[u] += __shfl_xor(acc[u], 8, 64);
        acc[u] += __shfl_xor(acc[u], 16, 64);
        acc[u] += __shfl_xor(acc[u], 32, 64);
    }

#pragma unroll
    for (int u = 0; u < 8; u++) acc[u] = fmaxf(acc[u], 0.f);

    float m = acc[0];
#pragma unroll
    for (int u = 1; u < 8; u++) m = fmaxf(m, acc[u]);
#pragma unroll
    for (int off = 1; off < 8; off <<= 1) m = fmaxf(m, __shfl_xor(m, off, 64));

    float ex[8];
    float s = 0.f;
#pragma unroll
    for (int u = 0; u < 8; u++) {
        ex[u] = __expf(acc[u] - m);
        s += ex[u];
    }
#pragma unroll
    for (int off = 1; off < 8; off <<= 1) s += __shfl_xor(s, off, 64);
    float inv = 1.0f / s;

    if (grp == 0) {
        if (flags[0]) {
            float* op = (float*)Out + (size_t)n * 64 + gl * 8;
            float4 v0, v1;
            v0.x = ex[0] * inv; v0.y = ex[1] * inv; v0.z = ex[2] * inv; v0.w = ex[3] * inv;
            v1.x = ex[4] * inv; v1.y = ex[5] * inv; v1.z = ex[6] * inv; v1.w = ex[7] * inv;
            *(float4*)(void*)op = v0;
            *(float4*)(void*)(op + 4) = v1;
        } else {
            short8 o;
#pragma unroll
            for (int u = 0; u < 8; u++) o[u] = (short)f2bf(ex[u] * inv);
            *(short8*)(void*)((unsigned short*)Out + (size_t)n * 64 + gl * 8) = o;
        }
    }
}

// ---------------- launch ----------------

extern "C" void kernel_launch(void* const* d_in, const int* in_sizes, int n_in,
                              void* d_out, int out_size, void* d_ws, size_t ws_size,
                              hipStream_t stream) {
    const void* X  = d_in[0];                       // [N,128] bf16 or fp32
    const int*  ei = (const int*)d_in[1];           // [2,E] int32 or int64
    const void* W1 = d_in[2];                       // [128,128]
    const void* W2 = d_in[3];                       // [128,128]
    const void* W3 = d_in[4];                       // [128,64]

    const int N = in_sizes[0] / 128;   // 50000
    const int E = in_sizes[1] / 2;     // 800000

    char* ws = (char*)d_ws;
    size_t off = 0;
    int* counts = (int*)(ws + off);   off += ws_align((size_t)N * 4);
    int* total  = (int*)(ws + off);   off += ws_align(64);
    const size_t zero_bytes = off;    // counts + total need zeroing
    int* flags    = (int*)(ws + off);   off += ws_align(64);
    int* rowptr   = (int*)(ws + off);   off += ws_align((size_t)N * 4);
    float* dinv   = (float*)(ws + off); off += ws_align((size_t)N * 4);
    int* loff     = (int*)(ws + off);   off += ws_align((size_t)E * 4);
    int2* edgedat = (int2*)(ws + off);  off += ws_align((size_t)E * 8);
    unsigned short* HA = (unsigned short*)(ws + off); off += ws_align((size_t)N * 128 * 2);
    unsigned short* HB = (unsigned short*)(ws + off); off += ws_align((size_t)N * 128 * 2);

    hipMemsetAsync(d_ws, 0, zero_bytes, stream);

    const int gblocks = (N + 127) / 128;       // 391
    const int hblocks = (E + 511) / 512;       // 1563
    const int sblocks = (N * 64 + 255) / 256;  // 12500

    // K1: gemm1 (X @ W1 -> HA, 512-thr 128-row blocks) || hist + flag publish
    gemm1_hist_kernel<<<gblocks + hblocks, 512, 0, stream>>>(
        X, (const unsigned short*)W1, ei, counts, loff, flags, HA, N, E, gblocks);
    alloc_kernel<<<(N + 255) / 256, 256, 0, stream>>>(counts, dinv, rowptr, total, N);
    fill_kernel<<<(E + 255) / 256, 256, 0, stream>>>(ei, flags, dinv, rowptr, loff, edgedat, E);

    // layer 1 aggregate: HB = relu(A_norm HA)
    spmm128_kernel<<<sblocks, 256, 0, stream>>>(edgedat, rowptr, counts, HA, HB, N);
    // layer 2
    gemm_kernel<128><<<gblocks, 512, 0, stream>>>(HB, W2, flags, HA, N);
    spmm128_kernel<<<sblocks, 256, 0, stream>>>(edgedat, rowptr, counts, HA, HB, N);
    // layer 3 (F_out = 64) + relu + softmax
    gemm_kernel<64><<<gblocks, 512, 0, stream>>>(HB, W3, flags, HA, N);
    spmm64_softmax_kernel<<<sblocks, 256, 0, stream>>>(edgedat, rowptr, counts, HA, flags, d_out, N);
}